// Round 1
// baseline (785.437 us; speedup 1.0000x reference)
//
#include <hip/hip_runtime.h>

#define N_NODES 20000
#define FEAT    128
#define SEQ     32
#define HEADS   4
#define HDIM    32
#define NT      8      // nodes per block
#define RS      132    // padded LDS row stride for 128-element rows (132*4B = 33*16B, keeps float4 alignment)
#define SS      36     // padded LDS row stride for 32-element rows  (36*4B = 9*16B)

__device__ __forceinline__ void fma4(float4& a, float s, const float4 b) {
    a.x = fmaf(s, b.x, a.x);
    a.y = fmaf(s, b.y, a.y);
    a.z = fmaf(s, b.z, a.z);
    a.w = fmaf(s, b.w, a.w);
}

// Prep: WkT[c][f] = Wk[f][c]  (64 KB, runs in ~2 us, enables coalesced column access in P2)
__global__ void transpose_wk(const float* __restrict__ Wk, float* __restrict__ WkT) {
    int tid = blockIdx.x * blockDim.x + threadIdx.x;   // 0..16383
    int c = tid >> 7, f = tid & 127;
    WkT[c * 128 + f] = Wk[f * 128 + c];
}

__global__ __launch_bounds__(256) void mha_fused(
    const float* __restrict__ query, const float* __restrict__ key,
    const float* __restrict__ value, const int* __restrict__ mask_idx,
    const float* __restrict__ Wq, const float* __restrict__ bq,
    const float* __restrict__ WkT, const float* __restrict__ bk,
    const float* __restrict__ Wv, const float* __restrict__ bv,
    const float* __restrict__ Wo, const float* __restrict__ bo,
    const float* __restrict__ gamma, const float* __restrict__ beta,
    float* __restrict__ out)
{
    __shared__ float qT[NT * RS];          // query tile (kept live for residual)
    __shared__ float qh[NT * RS];          // qhat; later reused as wv
    __shared__ float qk[NT * 4 * RS];      // per-node per-head folded query-key vector
    __shared__ float sc[NT * 4 * SS];      // scores -> attn, layout [nd][h][s]
    __shared__ float av[NT * 4 * RS];      // attention-weighted value sums
    __shared__ float ot[NT * RS];          // pre-LN output
    __shared__ float qbk[NT * 4];

    const int tid   = threadIdx.x;
    const int node0 = blockIdx.x * NT;
    const int ng = tid >> 5;               // node slot 0..7
    const int f4 = tid & 31;               // feature quad 0..31
    const int fo = f4 * 4;

    // ---------- P0: load query tile (coalesced float4) ----------
    {
        int i  = tid * 4;                  // flat 0..1023
        int nd = i >> 7, f = i & 127;
        float4 v = *(const float4*)&query[(long)(node0 + nd) * FEAT + f];
        *(float4*)&qT[nd * RS + f] = v;
    }
    __syncthreads();

    // ---------- P1: qhat = query @ Wq + bq ----------
    {
        float4 acc = {0.f, 0.f, 0.f, 0.f};
        for (int c = 0; c < 128; ++c) {
            float qv = qT[ng * RS + c];
            float4 w = *(const float4*)&Wq[c * 128 + fo];
            fma4(acc, qv, w);
        }
        float4 b = *(const float4*)&bq[fo];
        acc.x += b.x; acc.y += b.y; acc.z += b.z; acc.w += b.w;
        *(float4*)&qh[ng * RS + fo] = acc;
    }
    __syncthreads();

    // ---------- P2: qk[nd][h][f] = sum_d qhat[nd][h*32+d] * Wk[f][h*32+d]   (uses WkT) ----------
    {
        float4 acc[4];
        #pragma unroll
        for (int h = 0; h < 4; ++h) acc[h] = make_float4(0.f, 0.f, 0.f, 0.f);
        for (int d = 0; d < 32; ++d) {
            #pragma unroll
            for (int h = 0; h < 4; ++h) {
                float qv = qh[ng * RS + h * 32 + d];
                float4 w = *(const float4*)&WkT[(h * 32 + d) * 128 + fo];
                fma4(acc[h], qv, w);
            }
        }
        #pragma unroll
        for (int h = 0; h < 4; ++h)
            *(float4*)&qk[(ng * 4 + h) * RS + fo] = acc[h];
    }
    if (tid < 32) {   // qbk[nd][h] = qhat[nd][h-slice] . bk[h-slice]
        int nd = tid >> 2, h = tid & 3;
        float s = 0.f;
        for (int d = 0; d < 32; ++d)
            s = fmaf(qh[nd * RS + h * 32 + d], bk[h * 32 + d], s);
        qbk[nd * 4 + h] = s;
    }
    __syncthreads();

    // ---------- P3: raw scores:  sc[nd][h][s] = key[s,node,:] . qk[nd][h][:] ----------
    {
        const int s  = tid >> 3;   // 0..31
        const int q8 = tid & 7;    // 0..7, covers 16 features each
        const long kbase = ((long)s * N_NODES + node0) * FEAT + q8 * 16;
        for (int nd = 0; nd < NT; ++nd) {
            const float4 k0 = *(const float4*)&key[kbase + nd * FEAT + 0];
            const float4 k1 = *(const float4*)&key[kbase + nd * FEAT + 4];
            const float4 k2 = *(const float4*)&key[kbase + nd * FEAT + 8];
            const float4 k3 = *(const float4*)&key[kbase + nd * FEAT + 12];
            #pragma unroll
            for (int h = 0; h < 4; ++h) {
                const float* qkp = &qk[(nd * 4 + h) * RS + q8 * 16];
                float4 a0 = *(const float4*)&qkp[0];
                float4 a1 = *(const float4*)&qkp[4];
                float4 a2 = *(const float4*)&qkp[8];
                float4 a3 = *(const float4*)&qkp[12];
                float p = 0.f;
                p = fmaf(k0.x, a0.x, p); p = fmaf(k0.y, a0.y, p);
                p = fmaf(k0.z, a0.z, p); p = fmaf(k0.w, a0.w, p);
                p = fmaf(k1.x, a1.x, p); p = fmaf(k1.y, a1.y, p);
                p = fmaf(k1.z, a1.z, p); p = fmaf(k1.w, a1.w, p);
                p = fmaf(k2.x, a2.x, p); p = fmaf(k2.y, a2.y, p);
                p = fmaf(k2.z, a2.z, p); p = fmaf(k2.w, a2.w, p);
                p = fmaf(k3.x, a3.x, p); p = fmaf(k3.y, a3.y, p);
                p = fmaf(k3.z, a3.z, p); p = fmaf(k3.w, a3.w, p);
                p += __shfl_xor(p, 1);
                p += __shfl_xor(p, 2);
                p += __shfl_xor(p, 4);
                if (q8 == 0) sc[(nd * 4 + h) * SS + s] = p;
            }
        }
    }
    __syncthreads();

    // ---------- P3b: scale + bias + ragged mask + softmax over s (32 workers) ----------
    if (tid < 32) {
        const int nd = tid >> 2, h = tid & 3;
        const int mi = mask_idx[node0 + nd];
        const float qb = qbk[nd * 4 + h];
        const float scale = 0.17677669529663687f;   // 1/sqrt(32)
        float mx = -1e30f;
        for (int s2 = 0; s2 < 32; ++s2) {
            float v = (sc[(nd * 4 + h) * SS + s2] + qb) * scale;
            if (s2 >= mi) v += -1e9f;
            sc[(nd * 4 + h) * SS + s2] = v;
            mx = fmaxf(mx, v);
        }
        float sum = 0.f;
        for (int s2 = 0; s2 < 32; ++s2) {
            float e = __expf(sc[(nd * 4 + h) * SS + s2] - mx);
            sc[(nd * 4 + h) * SS + s2] = e;
            sum += e;
        }
        const float inv = 1.f / sum;
        for (int s2 = 0; s2 < 32; ++s2)
            sc[(nd * 4 + h) * SS + s2] *= inv;
    }
    __syncthreads();

    // ---------- P4: av[nd][h][f] = sum_s attn[nd][h][s] * value[s,node,f] ----------
    {
        float4 acc[4];
        #pragma unroll
        for (int h = 0; h < 4; ++h) acc[h] = make_float4(0.f, 0.f, 0.f, 0.f);
        const long vbase = (long)(node0 + ng) * FEAT + fo;
        for (int s2 = 0; s2 < 32; ++s2) {
            float4 vv = *(const float4*)&value[vbase + (long)s2 * N_NODES * FEAT];
            #pragma unroll
            for (int h = 0; h < 4; ++h) {
                float a = sc[(ng * 4 + h) * SS + s2];
                fma4(acc[h], a, vv);
            }
        }
        #pragma unroll
        for (int h = 0; h < 4; ++h)
            *(float4*)&av[(ng * 4 + h) * RS + fo] = acc[h];
    }
    __syncthreads();

    // ---------- P5: wv[nd][o] = sum_f av[nd][h(o)][f] * Wv[f][o] + bv[o]   (o = fo..fo+3, same head) ----------
    {
        const int h = fo >> 5;
        float4 acc = {0.f, 0.f, 0.f, 0.f};
        for (int f = 0; f < 128; ++f) {
            float a = av[(ng * 4 + h) * RS + f];
            float4 w = *(const float4*)&Wv[f * 128 + fo];
            fma4(acc, a, w);
        }
        float4 b = *(const float4*)&bv[fo];
        acc.x += b.x; acc.y += b.y; acc.z += b.z; acc.w += b.w;
        *(float4*)&qh[ng * RS + fo] = acc;   // reuse qh as wv
    }
    __syncthreads();

    // ---------- P6: pre-LN out = wv @ Wo + bo ----------
    {
        float4 acc = {0.f, 0.f, 0.f, 0.f};
        for (int c = 0; c < 128; ++c) {
            float wvv = qh[ng * RS + c];
            float4 w = *(const float4*)&Wo[c * 128 + fo];
            fma4(acc, wvv, w);
        }
        float4 b = *(const float4*)&bo[fo];
        acc.x += b.x; acc.y += b.y; acc.z += b.z; acc.w += b.w;
        *(float4*)&ot[ng * RS + fo] = acc;
    }
    __syncthreads();

    // ---------- P7: LayerNorm + residual, coalesced store ----------
    {
        float4 x = *(float4*)&ot[ng * RS + fo];
        float s1 = x.x + x.y + x.z + x.w;
        float s2 = x.x * x.x + x.y * x.y + x.z * x.z + x.w * x.w;
        #pragma unroll
        for (int off = 1; off < 32; off <<= 1) {
            s1 += __shfl_xor(s1, off);
            s2 += __shfl_xor(s2, off);
        }
        const float mu  = s1 * (1.f / 128.f);
        const float var = s2 * (1.f / 128.f) - mu * mu;
        const float rstd = rsqrtf(var + 1e-5f);
        float4 g = *(const float4*)&gamma[fo];
        float4 b = *(const float4*)&beta[fo];
        float4 q = *(float4*)&qT[ng * RS + fo];
        float4 r;
        r.x = (x.x - mu) * rstd * g.x + b.x + q.x;
        r.y = (x.y - mu) * rstd * g.y + b.y + q.y;
        r.z = (x.z - mu) * rstd * g.z + b.z + q.z;
        r.w = (x.w - mu) * rstd * g.w + b.w + q.w;
        *(float4*)&out[(long)(node0 + ng) * FEAT + fo] = r;
    }
}

extern "C" void kernel_launch(void* const* d_in, const int* in_sizes, int n_in,
                              void* d_out, int out_size, void* d_ws, size_t ws_size,
                              hipStream_t stream) {
    const float* query = (const float*)d_in[0];
    const float* key   = (const float*)d_in[1];
    const float* value = (const float*)d_in[2];
    const int*   midx  = (const int*)  d_in[3];
    const float* Wq    = (const float*)d_in[4];
    const float* bq    = (const float*)d_in[5];
    const float* Wk    = (const float*)d_in[6];
    const float* bk    = (const float*)d_in[7];
    const float* Wv    = (const float*)d_in[8];
    const float* bv    = (const float*)d_in[9];
    const float* Wo    = (const float*)d_in[10];
    const float* bo    = (const float*)d_in[11];
    const float* gamma = (const float*)d_in[12];
    const float* beta  = (const float*)d_in[13];

    float* WkT = (float*)d_ws;   // 64 KB scratch, rewritten every launch

    transpose_wk<<<64, 256, 0, stream>>>(Wk, WkT);
    mha_fused<<<N_NODES / NT, 256, 0, stream>>>(
        query, key, value, midx, Wq, bq, WkT, bk, Wv, bv, Wo, bo,
        gamma, beta, (float*)d_out);
}

// Round 2
// 719.225 us; speedup vs baseline: 1.0921x; 1.0921x over previous
//
#include <hip/hip_runtime.h>

#define N_NODES 20000
#define FEAT    128
#define SEQ     32
#define HEADS   4
#define HDIM    32
#define NT      8      // nodes per block
#define RS      132    // padded LDS row stride for 128-element rows (132*4B = 33*16B, float4-aligned)
#define SS      36     // padded LDS row stride for 32-element rows  (36*4B = 9*16B)

__device__ __forceinline__ void fma4(float4& a, float s, const float4 b) {
    a.x = fmaf(s, b.x, a.x);
    a.y = fmaf(s, b.y, a.y);
    a.z = fmaf(s, b.z, a.z);
    a.w = fmaf(s, b.w, a.w);
}

// Prep: WkT[c][f] = Wk[f][c]  (64 KB, ~2 us, enables coalesced column access in P2)
__global__ void transpose_wk(const float* __restrict__ Wk, float* __restrict__ WkT) {
    int tid = blockIdx.x * blockDim.x + threadIdx.x;   // 0..16383
    int c = tid >> 7, f = tid & 127;
    WkT[c * 128 + f] = Wk[f * 128 + c];
}

__global__ __launch_bounds__(256, 5) void mha_fused(
    const float* __restrict__ query, const float* __restrict__ key,
    const float* __restrict__ value, const int* __restrict__ mask_idx,
    const float* __restrict__ Wq, const float* __restrict__ bq,
    const float* __restrict__ WkT, const float* __restrict__ bk,
    const float* __restrict__ Wv, const float* __restrict__ bv,
    const float* __restrict__ Wo, const float* __restrict__ bo,
    const float* __restrict__ gamma, const float* __restrict__ beta,
    float* __restrict__ out)
{
    __shared__ float qT[NT * RS];          // query tile (live until residual)
    __shared__ float qh[NT * RS];          // qhat; later reused as wv
    __shared__ float qkav[NT * 4 * RS];    // qk vectors in P2/P3; av in P4/P5 (disjoint lifetimes)
    __shared__ float sc[NT * 4 * SS];      // scores -> attn, layout [nd*4+h][s]
    __shared__ float qbk[NT * 4];
    __shared__ int   Ls[NT];               // live seq length per node (mi==0 -> 32)
    __shared__ int   Mi[NT];

    const int tid   = threadIdx.x;
    const int node0 = blockIdx.x * NT;
    const int ng = tid >> 5;               // node slot 0..7
    const int f4 = tid & 31;               // feature quad 0..31
    const int fo = f4 * 4;

    // ---------- P0: load query tile (coalesced float4) + mask lengths ----------
    {
        int i  = tid * 4;                  // flat 0..1023
        int nd = i >> 7, f = i & 127;
        float4 v = *(const float4*)&query[(long)(node0 + nd) * FEAT + f];
        *(float4*)&qT[nd * RS + f] = v;
        if (tid < NT) {
            int m = mask_idx[node0 + tid];
            Mi[tid] = m;
            Ls[tid] = (m == 0) ? SEQ : m;  // mi==0: uniform -1e9 shift, all positions live
        }
    }
    __syncthreads();

    // ---------- P1: qhat = query @ Wq + bq ----------
    {
        float4 acc = {0.f, 0.f, 0.f, 0.f};
        for (int c = 0; c < 128; ++c) {
            float qv = qT[ng * RS + c];
            float4 w = *(const float4*)&Wq[c * 128 + fo];
            fma4(acc, qv, w);
        }
        float4 b = *(const float4*)&bq[fo];
        acc.x += b.x; acc.y += b.y; acc.z += b.z; acc.w += b.w;
        *(float4*)&qh[ng * RS + fo] = acc;
    }
    __syncthreads();

    // ---------- P2: qk[nd][h][f] = sum_d qhat[nd][h*32+d] * Wk[f][h*32+d]  (via WkT) ----------
    {
        float4 acc[4];
        #pragma unroll
        for (int h = 0; h < 4; ++h) acc[h] = make_float4(0.f, 0.f, 0.f, 0.f);
        for (int d = 0; d < 32; ++d) {
            #pragma unroll
            for (int h = 0; h < 4; ++h) {
                float qv = qh[ng * RS + h * 32 + d];
                float4 w = *(const float4*)&WkT[(h * 32 + d) * 128 + fo];
                fma4(acc[h], qv, w);
            }
        }
        #pragma unroll
        for (int h = 0; h < 4; ++h)
            *(float4*)&qkav[(ng * 4 + h) * RS + fo] = acc[h];
    }
    if (tid < 32) {   // qbk[nd*4+h] = qhat[nd][h-slice] . bk[h-slice]
        int nd = tid >> 2, h = tid & 3;
        float s = 0.f;
        for (int d = 0; d < 32; ++d)
            s = fmaf(qh[nd * RS + h * 32 + d], bk[h * 32 + d], s);
        qbk[tid] = s;
    }
    __syncthreads();

    // ---------- P3: raw scores only for live positions: sc[nd*4+h][s] = key[s,node,:].qk ----------
    {
        const int s  = tid >> 3;   // 0..31
        const int q8 = tid & 7;    // 0..7, 16 features each
        const long kbase = ((long)s * N_NODES + node0) * FEAT + q8 * 16;
        for (int nd = 0; nd < NT; ++nd) {
            if (s < Ls[nd]) {
                const float4 k0 = *(const float4*)&key[kbase + nd * FEAT + 0];
                const float4 k1 = *(const float4*)&key[kbase + nd * FEAT + 4];
                const float4 k2 = *(const float4*)&key[kbase + nd * FEAT + 8];
                const float4 k3 = *(const float4*)&key[kbase + nd * FEAT + 12];
                #pragma unroll
                for (int h = 0; h < 4; ++h) {
                    const float* qkp = &qkav[(nd * 4 + h) * RS + q8 * 16];
                    float4 a0 = *(const float4*)&qkp[0];
                    float4 a1 = *(const float4*)&qkp[4];
                    float4 a2 = *(const float4*)&qkp[8];
                    float4 a3 = *(const float4*)&qkp[12];
                    float p = 0.f;
                    p = fmaf(k0.x, a0.x, p); p = fmaf(k0.y, a0.y, p);
                    p = fmaf(k0.z, a0.z, p); p = fmaf(k0.w, a0.w, p);
                    p = fmaf(k1.x, a1.x, p); p = fmaf(k1.y, a1.y, p);
                    p = fmaf(k1.z, a1.z, p); p = fmaf(k1.w, a1.w, p);
                    p = fmaf(k2.x, a2.x, p); p = fmaf(k2.y, a2.y, p);
                    p = fmaf(k2.z, a2.z, p); p = fmaf(k2.w, a2.w, p);
                    p = fmaf(k3.x, a3.x, p); p = fmaf(k3.y, a3.y, p);
                    p = fmaf(k3.z, a3.z, p); p = fmaf(k3.w, a3.w, p);
                    p += __shfl_xor(p, 1);
                    p += __shfl_xor(p, 2);
                    p += __shfl_xor(p, 4);
                    if (q8 == 0) sc[(nd * 4 + h) * SS + s] = p;
                }
            }
        }
    }
    __syncthreads();

    // ---------- P3b: softmax over live positions, all 256 threads ----------
    // pair = (nd,h) row (32 rows), 8 lanes/row, 4 s-values/lane.
    {
        const int pair  = tid >> 3;          // nd*4+h
        const int lane8 = tid & 7;
        const int nd = pair >> 2;
        const int L  = Ls[nd];
        const bool mi0 = (Mi[nd] == 0);
        const float qb = qbk[pair];
        const float scale = 0.17677669529663687f;   // 1/sqrt(32)
        float v[4];
        #pragma unroll
        for (int i = 0; i < 4; ++i) {
            int s2 = lane8 * 4 + i;
            if (s2 < L) {
                float t = (sc[pair * SS + s2] + qb) * scale;
                if (mi0) t += -1e9f;        // same fp32 op order as R1 (verified numerics)
                v[i] = t;
            } else v[i] = -3.0e38f;
        }
        float mx = fmaxf(fmaxf(v[0], v[1]), fmaxf(v[2], v[3]));
        mx = fmaxf(mx, __shfl_xor(mx, 1));
        mx = fmaxf(mx, __shfl_xor(mx, 2));
        mx = fmaxf(mx, __shfl_xor(mx, 4));
        float e[4], sum = 0.f;
        #pragma unroll
        for (int i = 0; i < 4; ++i) {
            int s2 = lane8 * 4 + i;
            e[i] = (s2 < L) ? __expf(v[i] - mx) : 0.f;
            sum += e[i];
        }
        sum += __shfl_xor(sum, 1);
        sum += __shfl_xor(sum, 2);
        sum += __shfl_xor(sum, 4);
        const float inv = 1.f / sum;
        #pragma unroll
        for (int i = 0; i < 4; ++i) {
            int s2 = lane8 * 4 + i;
            if (s2 < L) sc[pair * SS + s2] = e[i] * inv;
        }
    }
    __syncthreads();

    // ---------- P4: av[nd][h][f] = sum_{s<L} attn[nd][h][s] * value[s,node,f]  (into qkav) ----------
    {
        float4 acc[4];
        #pragma unroll
        for (int h = 0; h < 4; ++h) acc[h] = make_float4(0.f, 0.f, 0.f, 0.f);
        const long vbase = (long)(node0 + ng) * FEAT + fo;
        const int L = Ls[ng];
        for (int s2 = 0; s2 < L; ++s2) {
            float4 vv = *(const float4*)&value[vbase + (long)s2 * N_NODES * FEAT];
            #pragma unroll
            for (int h = 0; h < 4; ++h) {
                float a = sc[(ng * 4 + h) * SS + s2];
                fma4(acc[h], a, vv);
            }
        }
        __syncthreads();   // ensure all P3-phase readers of qkav are done before overwrite
        #pragma unroll
        for (int h = 0; h < 4; ++h)
            *(float4*)&qkav[(ng * 4 + h) * RS + fo] = acc[h];
    }
    __syncthreads();

    // ---------- P5: wv[nd][o] = sum_f av[nd][h(o)][f] * Wv[f][o] + bv[o] ----------
    {
        const int h = fo >> 5;
        float4 acc = {0.f, 0.f, 0.f, 0.f};
        for (int f = 0; f < 128; ++f) {
            float a = qkav[(ng * 4 + h) * RS + f];
            float4 w = *(const float4*)&Wv[f * 128 + fo];
            fma4(acc, a, w);
        }
        float4 b = *(const float4*)&bv[fo];
        acc.x += b.x; acc.y += b.y; acc.z += b.z; acc.w += b.w;
        __syncthreads();                      // qh (qhat) dead; reuse as wv
        *(float4*)&qh[ng * RS + fo] = acc;
    }
    __syncthreads();

    // ---------- P6+P7: out = LN(wv @ Wo + bo) + query, all in registers ----------
    {
        float4 x = {0.f, 0.f, 0.f, 0.f};
        for (int c = 0; c < 128; ++c) {
            float wvv = qh[ng * RS + c];
            float4 w = *(const float4*)&Wo[c * 128 + fo];
            fma4(x, wvv, w);
        }
        float4 b = *(const float4*)&bo[fo];
        x.x += b.x; x.y += b.y; x.z += b.z; x.w += b.w;

        float s1 = x.x + x.y + x.z + x.w;
        float s2 = x.x * x.x + x.y * x.y + x.z * x.z + x.w * x.w;
        #pragma unroll
        for (int off = 1; off < 32; off <<= 1) {
            s1 += __shfl_xor(s1, off);
            s2 += __shfl_xor(s2, off);
        }
        const float mu  = s1 * (1.f / 128.f);
        const float var = s2 * (1.f / 128.f) - mu * mu;
        const float rstd = rsqrtf(var + 1e-5f);
        float4 g = *(const float4*)&gamma[fo];
        float4 bt = *(const float4*)&beta[fo];
        float4 q = *(float4*)&qT[ng * RS + fo];
        float4 r;
        r.x = (x.x - mu) * rstd * g.x + bt.x + q.x;
        r.y = (x.y - mu) * rstd * g.y + bt.y + q.y;
        r.z = (x.z - mu) * rstd * g.z + bt.z + q.z;
        r.w = (x.w - mu) * rstd * g.w + bt.w + q.w;
        *(float4*)&out[(long)(node0 + ng) * FEAT + fo] = r;
    }
}

extern "C" void kernel_launch(void* const* d_in, const int* in_sizes, int n_in,
                              void* d_out, int out_size, void* d_ws, size_t ws_size,
                              hipStream_t stream) {
    const float* query = (const float*)d_in[0];
    const float* key   = (const float*)d_in[1];
    const float* value = (const float*)d_in[2];
    const int*   midx  = (const int*)  d_in[3];
    const float* Wq    = (const float*)d_in[4];
    const float* bq    = (const float*)d_in[5];
    const float* Wk    = (const float*)d_in[6];
    const float* bk    = (const float*)d_in[7];
    const float* Wv    = (const float*)d_in[8];
    const float* bv    = (const float*)d_in[9];
    const float* Wo    = (const float*)d_in[10];
    const float* bo    = (const float*)d_in[11];
    const float* gamma = (const float*)d_in[12];
    const float* beta  = (const float*)d_in[13];

    float* WkT = (float*)d_ws;   // 64 KB scratch, rewritten every launch

    transpose_wk<<<64, 256, 0, stream>>>(Wk, WkT);
    mha_fused<<<N_NODES / NT, 256, 0, stream>>>(
        query, key, value, midx, Wq, bq, WkT, bk, Wv, bv, Wo, bo,
        gamma, beta, (float*)d_out);
}